// Round 2
// baseline (411.499 us; speedup 1.0000x reference)
//
#include <hip/hip_runtime.h>

#define D 64

__device__ __forceinline__ float rlane(float v, int l) {
    return __int_as_float(__builtin_amdgcn_readlane(__float_as_int(v), l));
}

// ---------------------------------------------------------------------------
// Phase 1a: deg[dst]++  (int atomics on 200KB, L2-resident, cheap)
// ---------------------------------------------------------------------------
__global__ __launch_bounds__(256) void hist_kernel(
    const int* __restrict__ edge_dst, int* __restrict__ deg, int n_edges)
{
    int e = blockIdx.x * 256 + threadIdx.x;
    if (e >= n_edges) return;
    atomicAdd(&deg[edge_dst[e]], 1);
}

// ---------------------------------------------------------------------------
// Phase 1b: exclusive scan of deg -> offsets (n+1) and cursor copy.
// Single block, 1024 threads, each owns a contiguous chunk.
// ---------------------------------------------------------------------------
__global__ __launch_bounds__(1024) void scan_kernel(
    const int* __restrict__ deg, int* __restrict__ offsets,
    int* __restrict__ cursor, int n, int n_edges)
{
    __shared__ int part[1024];
    int t = threadIdx.x;
    int C = (n + 1023) >> 10;
    int base = t * C;
    int s = 0;
    for (int c = 0; c < C; ++c) {
        int i = base + c;
        if (i < n) s += deg[i];
    }
    part[t] = s;
    __syncthreads();
    // Hillis-Steele inclusive scan over 1024 partials
    for (int off = 1; off < 1024; off <<= 1) {
        int v = 0;
        if (t >= off) v = part[t - off];
        __syncthreads();
        if (t >= off) part[t] += v;
        __syncthreads();
    }
    int run = (t == 0) ? 0 : part[t - 1];
    for (int c = 0; c < C; ++c) {
        int i = base + c;
        if (i < n) {
            offsets[i] = run;
            cursor[i]  = run;
            run += deg[i];
        }
    }
    if (t == 0) offsets[n] = n_edges;
}

// ---------------------------------------------------------------------------
// Phase 1c: bucket edges: csr_sw[pos] = (src, weight_bits)
// ---------------------------------------------------------------------------
__global__ __launch_bounds__(256) void fill_kernel(
    const int* __restrict__ edge_src, const int* __restrict__ edge_dst,
    const float* __restrict__ edge_weight,
    int* __restrict__ cursor, int2* __restrict__ csr_sw, int n_edges)
{
    int e = blockIdx.x * 256 + threadIdx.x;
    if (e >= n_edges) return;
    int d = edge_dst[e];
    int pos = atomicAdd(&cursor[d], 1);
    csr_sw[pos] = make_int2(edge_src[e], __float_as_int(edge_weight[e]));
}

// ---------------------------------------------------------------------------
// Phase 2: wave-per-node gather: neighbor[i] = sum_e w_e * features[src_e]
// No atomics; edge metadata loaded from uniform (readfirstlane'd) addresses,
// feature rows read 256B-coalesced (lane = dim). Written exactly once.
// ---------------------------------------------------------------------------
__global__ __launch_bounds__(256) void gather_kernel(
    const float* __restrict__ features, const int2* __restrict__ csr_sw,
    const int* __restrict__ offsets, float* __restrict__ neighbor, int n_nodes)
{
    int lane = threadIdx.x & 63;
    int gw = (blockIdx.x * 256 + threadIdx.x) >> 6;
    int nw = (gridDim.x * 256) >> 6;
    for (int i = gw; i < n_nodes; i += nw) {
        int beg = __builtin_amdgcn_readfirstlane(offsets[i]);
        int end = __builtin_amdgcn_readfirstlane(offsets[i + 1]);
        float acc = 0.f;
        for (int j = beg; j < end; ++j) {
            int2 p = csr_sw[j];   // wave-uniform address
            acc = fmaf(__int_as_float(p.y),
                       features[(size_t)p.x * D + lane], acc);
        }
        neighbor[(size_t)i * D + lane] = acc;
    }
}

// ---------------------------------------------------------------------------
// Phase 3: out = normalize([features | neighbor] @ W^T + b)
// Lane o holds the entire W row o (128 floats) in VGPRs (all static indexing).
// Combined row broadcast via v_readlane (VALU pipe) -> zero DS ops in the
// hot loop. 256 fma + 128 readlane per node per lane.
// ---------------------------------------------------------------------------
__global__ __launch_bounds__(256) void gemm_norm_kernel(
    const float* __restrict__ features, const float* __restrict__ neighbor,
    const float* __restrict__ W, const float* __restrict__ bias,
    float* __restrict__ out, int n_nodes)
{
    int lane = threadIdx.x & 63;
    // W row `lane` into registers (fully unrolled -> SROA to VGPRs)
    float wr[128];
    const float4* Wv = (const float4*)(W + (size_t)lane * 128);
    #pragma unroll
    for (int q = 0; q < 32; ++q) {
        float4 v = Wv[q];
        wr[4 * q + 0] = v.x; wr[4 * q + 1] = v.y;
        wr[4 * q + 2] = v.z; wr[4 * q + 3] = v.w;
    }
    float bl = bias[lane];

    int gw = (blockIdx.x * 256 + threadIdx.x) >> 6;
    int nw = (gridDim.x * 256) >> 6;
    for (int i = gw; i < n_nodes; i += nw) {
        float cf = features[(size_t)i * D + lane];
        float cn = neighbor[(size_t)i * D + lane];
        float acc = bl;
        #pragma unroll
        for (int k = 0; k < 64; ++k)
            acc = fmaf(rlane(cf, k), wr[k], acc);
        #pragma unroll
        for (int k = 0; k < 64; ++k)
            acc = fmaf(rlane(cn, k), wr[64 + k], acc);
        float s = acc * acc;
        #pragma unroll
        for (int m = 1; m < 64; m <<= 1) s += __shfl_xor(s, m, 64);
        out[(size_t)i * D + lane] = acc / fmaxf(sqrtf(s), 1e-12f);
    }
}

extern "C" void kernel_launch(void* const* d_in, const int* in_sizes, int n_in,
                              void* d_out, int out_size, void* d_ws, size_t ws_size,
                              hipStream_t stream) {
    const float* features    = (const float*)d_in[0];
    const int*   edge_src    = (const int*)d_in[1];
    const int*   edge_dst    = (const int*)d_in[2];
    const float* edge_weight = (const float*)d_in[3];
    const float* W           = (const float*)d_in[4];
    const float* b           = (const float*)d_in[5];
    float*       out         = (float*)d_out;

    int n = in_sizes[0] / D;
    int E = in_sizes[1];

    // workspace layout (16B-aligned slabs)
    char* ws = (char*)d_ws;
    size_t szn  = (((size_t)n * 4) + 15) & ~(size_t)15;
    size_t szn1 = (((size_t)(n + 1) * 4) + 15) & ~(size_t)15;
    int*  deg      = (int*)(ws);
    int*  cursor   = (int*)(ws + szn);
    int*  offsets  = (int*)(ws + 2 * szn);
    int2* csr_sw   = (int2*)(ws + 2 * szn + szn1);
    float* neighbor = (float*)(ws + 2 * szn + szn1 + (size_t)E * 8);

    hipMemsetAsync(deg, 0, (size_t)n * 4, stream);

    int eblocks = (E + 255) / 256;
    hist_kernel<<<eblocks, 256, 0, stream>>>(edge_dst, deg, E);
    scan_kernel<<<1, 1024, 0, stream>>>(deg, offsets, cursor, n, E);
    fill_kernel<<<eblocks, 256, 0, stream>>>(edge_src, edge_dst, edge_weight,
                                             cursor, csr_sw, E);
    gather_kernel<<<1024, 256, 0, stream>>>(features, csr_sw, offsets,
                                            neighbor, n);
    gemm_norm_kernel<<<512, 256, 0, stream>>>(features, neighbor, W, b, out, n);
}

// Round 4
// 241.314 us; speedup vs baseline: 1.7052x; 1.7052x over previous
//
#include <hip/hip_runtime.h>

#define D 64
#define TILE 1024

__device__ __forceinline__ float rlane(float v, int l) {
    return __int_as_float(__builtin_amdgcn_readlane(__float_as_int(v), l));
}

// ---------------------------------------------------------------------------
// Phase 1a: deg[dst]++  (int atomics on 200KB, L2-resident)
// ---------------------------------------------------------------------------
__global__ __launch_bounds__(256) void hist_kernel(
    const int* __restrict__ edge_dst, int* __restrict__ deg, int n_edges)
{
    int e = blockIdx.x * 256 + threadIdx.x;
    if (e < n_edges) atomicAdd(&deg[edge_dst[e]], 1);
}

// ---------------------------------------------------------------------------
// Phase 1b-i: per-tile (1024 elems) sums. int4 loads, shfl reduce.
// ---------------------------------------------------------------------------
__global__ __launch_bounds__(256) void tile_sum_kernel(
    const int* __restrict__ deg, int* __restrict__ partial, int n)
{
    int t = threadIdx.x;
    int base = blockIdx.x * TILE + t * 4;
    int s = 0;
    if (base + 3 < n) {
        int4 v = *(const int4*)(deg + base);
        s = v.x + v.y + v.z + v.w;
    } else {
        for (int k = 0; k < 4; ++k) if (base + k < n) s += deg[base + k];
    }
    #pragma unroll
    for (int off = 1; off < 64; off <<= 1) s += __shfl_xor(s, off, 64);
    __shared__ int wsum[4];
    int lane = t & 63, wv = t >> 6;
    if (lane == 0) wsum[wv] = s;
    __syncthreads();
    if (t == 0) partial[blockIdx.x] = wsum[0] + wsum[1] + wsum[2] + wsum[3];
}

// ---------------------------------------------------------------------------
// Phase 1b-ii: exclusive scan of tile partials (1 block, 64 lanes, shfl_up;
// carry loop handles any tile count). Also writes offsets[n] = E.
// ---------------------------------------------------------------------------
__global__ __launch_bounds__(64) void scan_partial_kernel(
    const int* __restrict__ partial, int* __restrict__ ppref, int nb,
    int* __restrict__ offsets, int n, int n_edges)
{
    int lane = threadIdx.x;
    int carry = 0;
    for (int base = 0; base < nb; base += 64) {
        int idx = base + lane;
        int v = (idx < nb) ? partial[idx] : 0;
        int inc = v;
        #pragma unroll
        for (int off = 1; off < 64; off <<= 1) {
            int u = __shfl_up(inc, off, 64);
            if (lane >= off) inc += u;
        }
        if (idx < nb) ppref[idx] = carry + inc - v;   // exclusive prefix
        carry += __shfl(inc, 63, 64);
    }
    if (lane == 0) offsets[n] = n_edges;
}

// ---------------------------------------------------------------------------
// Phase 1b-iii: per-tile scan -> offsets + cursor.
// ---------------------------------------------------------------------------
__global__ __launch_bounds__(256) void scan_tile_kernel(
    const int* __restrict__ deg, const int* __restrict__ ppref,
    int* __restrict__ offsets, int* __restrict__ cursor, int n)
{
    int t = threadIdx.x;
    int base = blockIdx.x * TILE + t * 4;
    int e0 = 0, e1 = 0, e2 = 0, e3 = 0;
    if (base + 3 < n) {
        int4 v = *(const int4*)(deg + base);
        e0 = v.x; e1 = v.y; e2 = v.z; e3 = v.w;
    } else {
        if (base + 0 < n) e0 = deg[base + 0];
        if (base + 1 < n) e1 = deg[base + 1];
        if (base + 2 < n) e2 = deg[base + 2];
        if (base + 3 < n) e3 = deg[base + 3];
    }
    int s = e0 + e1 + e2 + e3;
    int inc = s;
    int lane = t & 63, wv = t >> 6;
    #pragma unroll
    for (int off = 1; off < 64; off <<= 1) {
        int u = __shfl_up(inc, off, 64);
        if (lane >= off) inc += u;
    }
    __shared__ int wsum[4];
    if (lane == 63) wsum[wv] = inc;
    __syncthreads();
    int wpre = 0;
    for (int wq = 0; wq < wv; ++wq) wpre += wsum[wq];
    int excl = ppref[blockIdx.x] + wpre + inc - s;
    int o0 = excl, o1 = o0 + e0, o2 = o1 + e1, o3 = o2 + e2;
    if (base + 0 < n) { offsets[base + 0] = o0; cursor[base + 0] = o0; }
    if (base + 1 < n) { offsets[base + 1] = o1; cursor[base + 1] = o1; }
    if (base + 2 < n) { offsets[base + 2] = o2; cursor[base + 2] = o2; }
    if (base + 3 < n) { offsets[base + 3] = o3; cursor[base + 3] = o3; }
}

// ---------------------------------------------------------------------------
// Phase 1c: bucket edges: csr_sw[pos] = (src, weight_bits)
// ---------------------------------------------------------------------------
__global__ __launch_bounds__(256) void fill_kernel(
    const int* __restrict__ edge_src, const int* __restrict__ edge_dst,
    const float* __restrict__ edge_weight,
    int* __restrict__ cursor, int2* __restrict__ csr_sw, int n_edges)
{
    int e = blockIdx.x * 256 + threadIdx.x;
    if (e >= n_edges) return;
    int d = edge_dst[e];
    int pos = atomicAdd(&cursor[d], 1);
    csr_sw[pos] = make_int2(edge_src[e], __float_as_int(edge_weight[e]));
}

// ---------------------------------------------------------------------------
// Phase 2: wave-per-node gather, 4-deep ILP so 4 csr entries + 4 feature rows
// are in flight concurrently (was a serial 2-deep chain per edge).
// ---------------------------------------------------------------------------
__global__ __launch_bounds__(256) void gather_kernel(
    const float* __restrict__ features, const int2* __restrict__ csr_sw,
    const int* __restrict__ offsets, float* __restrict__ neighbor, int n_nodes)
{
    int lane = threadIdx.x & 63;
    int gw = (blockIdx.x * 256 + threadIdx.x) >> 6;
    int nw = (gridDim.x * 256) >> 6;
    for (int i = gw; i < n_nodes; i += nw) {
        int beg = __builtin_amdgcn_readfirstlane(offsets[i]);
        int end = __builtin_amdgcn_readfirstlane(offsets[i + 1]);
        float acc = 0.f;
        int j = beg;
        for (; j + 3 < end; j += 4) {
            int2 p0 = csr_sw[j + 0];
            int2 p1 = csr_sw[j + 1];
            int2 p2 = csr_sw[j + 2];
            int2 p3 = csr_sw[j + 3];
            float a0 = features[(size_t)p0.x * D + lane];
            float a1 = features[(size_t)p1.x * D + lane];
            float a2 = features[(size_t)p2.x * D + lane];
            float a3 = features[(size_t)p3.x * D + lane];
            acc = fmaf(__int_as_float(p0.y), a0, acc);
            acc = fmaf(__int_as_float(p1.y), a1, acc);
            acc = fmaf(__int_as_float(p2.y), a2, acc);
            acc = fmaf(__int_as_float(p3.y), a3, acc);
        }
        for (; j < end; ++j) {
            int2 p = csr_sw[j];
            acc = fmaf(__int_as_float(p.y), features[(size_t)p.x * D + lane], acc);
        }
        neighbor[(size_t)i * D + lane] = acc;
    }
}

// ---------------------------------------------------------------------------
// Phase 3: out = normalize([features | neighbor] @ W^T + b)
// Lane o holds W row o (128 floats) in VGPRs; broadcast via v_readlane.
// ---------------------------------------------------------------------------
__global__ __launch_bounds__(256) void gemm_norm_kernel(
    const float* __restrict__ features, const float* __restrict__ neighbor,
    const float* __restrict__ W, const float* __restrict__ bias,
    float* __restrict__ out, int n_nodes)
{
    int lane = threadIdx.x & 63;
    float wr[128];
    const float4* Wv = (const float4*)(W + (size_t)lane * 128);
    #pragma unroll
    for (int q = 0; q < 32; ++q) {
        float4 v = Wv[q];
        wr[4 * q + 0] = v.x; wr[4 * q + 1] = v.y;
        wr[4 * q + 2] = v.z; wr[4 * q + 3] = v.w;
    }
    float bl = bias[lane];

    int gw = (blockIdx.x * 256 + threadIdx.x) >> 6;
    int nw = (gridDim.x * 256) >> 6;
    for (int i = gw; i < n_nodes; i += nw) {
        float cf = features[(size_t)i * D + lane];
        float cn = neighbor[(size_t)i * D + lane];
        float acc = bl;
        #pragma unroll
        for (int k = 0; k < 64; ++k)
            acc = fmaf(rlane(cf, k), wr[k], acc);
        #pragma unroll
        for (int k = 0; k < 64; ++k)
            acc = fmaf(rlane(cn, k), wr[64 + k], acc);
        float s = acc * acc;
        #pragma unroll
        for (int m = 1; m < 64; m <<= 1) s += __shfl_xor(s, m, 64);
        out[(size_t)i * D + lane] = acc / fmaxf(sqrtf(s), 1e-12f);
    }
}

extern "C" void kernel_launch(void* const* d_in, const int* in_sizes, int n_in,
                              void* d_out, int out_size, void* d_ws, size_t ws_size,
                              hipStream_t stream) {
    const float* features    = (const float*)d_in[0];
    const int*   edge_src    = (const int*)d_in[1];
    const int*   edge_dst    = (const int*)d_in[2];
    const float* edge_weight = (const float*)d_in[3];
    const float* W           = (const float*)d_in[4];
    const float* b           = (const float*)d_in[5];
    float*       out         = (float*)d_out;

    int n = in_sizes[0] / D;
    int E = in_sizes[1];
    int nb = (n + TILE - 1) / TILE;

    // workspace layout (256B-aligned slabs)
    char* ws = (char*)d_ws;
    auto al = [](size_t x) { return (x + 255) & ~(size_t)255; };
    size_t o = 0;
    int* deg      = (int*)(ws + o); o += al((size_t)n * 4);
    int* cursor   = (int*)(ws + o); o += al((size_t)n * 4);
    int* offsets  = (int*)(ws + o); o += al((size_t)(n + 1) * 4);
    int* partial  = (int*)(ws + o); o += al((size_t)nb * 4);
    int* ppref    = (int*)(ws + o); o += al((size_t)nb * 4);
    int2* csr_sw  = (int2*)(ws + o); o += al((size_t)E * 8);
    float* neighbor = (float*)(ws + o);

    hipMemsetAsync(deg, 0, (size_t)n * 4, stream);

    int eblocks = (E + 255) / 256;
    hist_kernel<<<eblocks, 256, 0, stream>>>(edge_dst, deg, E);
    tile_sum_kernel<<<nb, 256, 0, stream>>>(deg, partial, n);
    scan_partial_kernel<<<1, 64, 0, stream>>>(partial, ppref, nb, offsets, n, E);
    scan_tile_kernel<<<nb, 256, 0, stream>>>(deg, ppref, offsets, cursor, n);
    fill_kernel<<<eblocks, 256, 0, stream>>>(edge_src, edge_dst, edge_weight,
                                             cursor, csr_sw, E);
    gather_kernel<<<2048, 256, 0, stream>>>(features, csr_sw, offsets,
                                            neighbor, n);
    gemm_norm_kernel<<<1024, 256, 0, stream>>>(features, neighbor, W, b, out, n);
}

// Round 5
// 227.844 us; speedup vs baseline: 1.8061x; 1.0591x over previous
//
#include <hip/hip_runtime.h>

#define D 64
#define TILE 1024
#define RB 8              // dst ranges == XCD count
#define EPT 4             // edges per thread in scan kernels
#define CHUNK_E (256 * EPT)

__device__ __forceinline__ float rlane(float v, int l) {
    return __int_as_float(__builtin_amdgcn_readlane(__float_as_int(v), l));
}

// ---------------------------------------------------------------------------
// Phase 1a: deg[dst]++ — range-partitioned: block (chunk = b>>3, range = b&7).
// All chunks of residue r presumably land on XCD r (blockIdx%8 round-robin),
// keeping deg-range atomics XCD-local. Correct regardless of mapping.
// ---------------------------------------------------------------------------
__global__ __launch_bounds__(256) void hist_kernel(
    const int* __restrict__ edge_dst, int* __restrict__ deg,
    int n_edges, int n_nodes)
{
    int r = blockIdx.x & (RB - 1);
    int chunk = blockIdx.x >> 3;
    int lo = (int)((long long)r * n_nodes / RB);
    int hi = (int)((long long)(r + 1) * n_nodes / RB);
    int base = chunk * CHUNK_E + threadIdx.x * EPT;
    int d[EPT];
    if (base + EPT - 1 < n_edges) {
        int4 v = *(const int4*)(edge_dst + base);
        d[0] = v.x; d[1] = v.y; d[2] = v.z; d[3] = v.w;
    } else {
        #pragma unroll
        for (int k = 0; k < EPT; ++k)
            d[k] = (base + k < n_edges) ? edge_dst[base + k] : -1;
    }
    #pragma unroll
    for (int k = 0; k < EPT; ++k)
        if (d[k] >= lo && d[k] < hi) atomicAdd(&deg[d[k]], 1);
}

// ---------------------------------------------------------------------------
// Phase 1b-i: per-tile (1024 elems) sums. int4 loads, shfl reduce.
// ---------------------------------------------------------------------------
__global__ __launch_bounds__(256) void tile_sum_kernel(
    const int* __restrict__ deg, int* __restrict__ partial, int n)
{
    int t = threadIdx.x;
    int base = blockIdx.x * TILE + t * 4;
    int s = 0;
    if (base + 3 < n) {
        int4 v = *(const int4*)(deg + base);
        s = v.x + v.y + v.z + v.w;
    } else {
        for (int k = 0; k < 4; ++k) if (base + k < n) s += deg[base + k];
    }
    #pragma unroll
    for (int off = 1; off < 64; off <<= 1) s += __shfl_xor(s, off, 64);
    __shared__ int wsum[4];
    int lane = t & 63, wv = t >> 6;
    if (lane == 0) wsum[wv] = s;
    __syncthreads();
    if (t == 0) partial[blockIdx.x] = wsum[0] + wsum[1] + wsum[2] + wsum[3];
}

// ---------------------------------------------------------------------------
// Phase 1b-ii: exclusive scan of tile partials (1 block, 64 lanes).
// ---------------------------------------------------------------------------
__global__ __launch_bounds__(64) void scan_partial_kernel(
    const int* __restrict__ partial, int* __restrict__ ppref, int nb,
    int* __restrict__ offsets, int n, int n_edges)
{
    int lane = threadIdx.x;
    int carry = 0;
    for (int base = 0; base < nb; base += 64) {
        int idx = base + lane;
        int v = (idx < nb) ? partial[idx] : 0;
        int inc = v;
        #pragma unroll
        for (int off = 1; off < 64; off <<= 1) {
            int u = __shfl_up(inc, off, 64);
            if (lane >= off) inc += u;
        }
        if (idx < nb) ppref[idx] = carry + inc - v;
        carry += __shfl(inc, 63, 64);
    }
    if (lane == 0) offsets[n] = n_edges;
}

// ---------------------------------------------------------------------------
// Phase 1b-iii: per-tile scan -> offsets + cursor.
// ---------------------------------------------------------------------------
__global__ __launch_bounds__(256) void scan_tile_kernel(
    const int* __restrict__ deg, const int* __restrict__ ppref,
    int* __restrict__ offsets, int* __restrict__ cursor, int n)
{
    int t = threadIdx.x;
    int base = blockIdx.x * TILE + t * 4;
    int e0 = 0, e1 = 0, e2 = 0, e3 = 0;
    if (base + 3 < n) {
        int4 v = *(const int4*)(deg + base);
        e0 = v.x; e1 = v.y; e2 = v.z; e3 = v.w;
    } else {
        if (base + 0 < n) e0 = deg[base + 0];
        if (base + 1 < n) e1 = deg[base + 1];
        if (base + 2 < n) e2 = deg[base + 2];
        if (base + 3 < n) e3 = deg[base + 3];
    }
    int s = e0 + e1 + e2 + e3;
    int inc = s;
    int lane = t & 63, wv = t >> 6;
    #pragma unroll
    for (int off = 1; off < 64; off <<= 1) {
        int u = __shfl_up(inc, off, 64);
        if (lane >= off) inc += u;
    }
    __shared__ int wsum[4];
    if (lane == 63) wsum[wv] = inc;
    __syncthreads();
    int wpre = 0;
    for (int wq = 0; wq < wv; ++wq) wpre += wsum[wq];
    int excl = ppref[blockIdx.x] + wpre + inc - s;
    int o0 = excl, o1 = o0 + e0, o2 = o1 + e1, o3 = o2 + e2;
    if (base + 0 < n) { offsets[base + 0] = o0; cursor[base + 0] = o0; }
    if (base + 1 < n) { offsets[base + 1] = o1; cursor[base + 1] = o1; }
    if (base + 2 < n) { offsets[base + 2] = o2; cursor[base + 2] = o2; }
    if (base + 3 < n) { offsets[base + 3] = o3; cursor[base + 3] = o3; }
}

// ---------------------------------------------------------------------------
// Phase 1c: CSR fill, range-partitioned like hist. Block with residue r only
// writes csr positions for dst in range r (~E/8 entries = 800KB region) ->
// the owning XCD's L2 keeps the partition resident, writes coalesce to full
// lines before eviction. src/w loaded only under the match mask.
// ---------------------------------------------------------------------------
__global__ __launch_bounds__(256) void fill_kernel(
    const int* __restrict__ edge_src, const int* __restrict__ edge_dst,
    const float* __restrict__ edge_weight,
    int* __restrict__ cursor, int2* __restrict__ csr_sw,
    int n_edges, int n_nodes)
{
    int r = blockIdx.x & (RB - 1);
    int chunk = blockIdx.x >> 3;
    int lo = (int)((long long)r * n_nodes / RB);
    int hi = (int)((long long)(r + 1) * n_nodes / RB);
    int base = chunk * CHUNK_E + threadIdx.x * EPT;
    int d[EPT];
    if (base + EPT - 1 < n_edges) {
        int4 v = *(const int4*)(edge_dst + base);
        d[0] = v.x; d[1] = v.y; d[2] = v.z; d[3] = v.w;
    } else {
        #pragma unroll
        for (int k = 0; k < EPT; ++k)
            d[k] = (base + k < n_edges) ? edge_dst[base + k] : -1;
    }
    #pragma unroll
    for (int k = 0; k < EPT; ++k) {
        int dk = d[k];
        if (dk >= lo && dk < hi) {
            int e = base + k;
            int pos = atomicAdd(&cursor[dk], 1);
            csr_sw[pos] = make_int2(edge_src[e], __float_as_int(edge_weight[e]));
        }
    }
}

// ---------------------------------------------------------------------------
// Phase 2: wave-per-node gather, 8-deep ILP. csr reads are wave-uniform
// (s_load path); feature rows 256B-coalesced.
// ---------------------------------------------------------------------------
__global__ __launch_bounds__(256) void gather_kernel(
    const float* __restrict__ features, const int2* __restrict__ csr_sw,
    const int* __restrict__ offsets, float* __restrict__ neighbor, int n_nodes)
{
    int lane = threadIdx.x & 63;
    int gw = (blockIdx.x * 256 + threadIdx.x) >> 6;
    int nw = (gridDim.x * 256) >> 6;
    for (int i = gw; i < n_nodes; i += nw) {
        int beg = __builtin_amdgcn_readfirstlane(offsets[i]);
        int end = __builtin_amdgcn_readfirstlane(offsets[i + 1]);
        float acc = 0.f;
        int j = beg;
        for (; j + 7 < end; j += 8) {
            int2 p[8];
            float a[8];
            #pragma unroll
            for (int q = 0; q < 8; ++q) p[q] = csr_sw[j + q];
            #pragma unroll
            for (int q = 0; q < 8; ++q)
                a[q] = features[(size_t)p[q].x * D + lane];
            #pragma unroll
            for (int q = 0; q < 8; ++q)
                acc = fmaf(__int_as_float(p[q].y), a[q], acc);
        }
        for (; j < end; ++j) {
            int2 p = csr_sw[j];
            acc = fmaf(__int_as_float(p.y), features[(size_t)p.x * D + lane], acc);
        }
        neighbor[(size_t)i * D + lane] = acc;
    }
}

// ---------------------------------------------------------------------------
// Phase 3: out = normalize([features | neighbor] @ W^T + b)
// Lane o holds W row o (128 floats) in VGPRs; broadcast via v_readlane.
// ---------------------------------------------------------------------------
__global__ __launch_bounds__(256) void gemm_norm_kernel(
    const float* __restrict__ features, const float* __restrict__ neighbor,
    const float* __restrict__ W, const float* __restrict__ bias,
    float* __restrict__ out, int n_nodes)
{
    int lane = threadIdx.x & 63;
    float wr[128];
    const float4* Wv = (const float4*)(W + (size_t)lane * 128);
    #pragma unroll
    for (int q = 0; q < 32; ++q) {
        float4 v = Wv[q];
        wr[4 * q + 0] = v.x; wr[4 * q + 1] = v.y;
        wr[4 * q + 2] = v.z; wr[4 * q + 3] = v.w;
    }
    float bl = bias[lane];

    int gw = (blockIdx.x * 256 + threadIdx.x) >> 6;
    int nw = (gridDim.x * 256) >> 6;
    for (int i = gw; i < n_nodes; i += nw) {
        float cf = features[(size_t)i * D + lane];
        float cn = neighbor[(size_t)i * D + lane];
        float acc = bl;
        #pragma unroll
        for (int k = 0; k < 64; ++k)
            acc = fmaf(rlane(cf, k), wr[k], acc);
        #pragma unroll
        for (int k = 0; k < 64; ++k)
            acc = fmaf(rlane(cn, k), wr[64 + k], acc);
        float s = acc * acc;
        #pragma unroll
        for (int m = 1; m < 64; m <<= 1) s += __shfl_xor(s, m, 64);
        out[(size_t)i * D + lane] = acc / fmaxf(sqrtf(s), 1e-12f);
    }
}

extern "C" void kernel_launch(void* const* d_in, const int* in_sizes, int n_in,
                              void* d_out, int out_size, void* d_ws, size_t ws_size,
                              hipStream_t stream) {
    const float* features    = (const float*)d_in[0];
    const int*   edge_src    = (const int*)d_in[1];
    const int*   edge_dst    = (const int*)d_in[2];
    const float* edge_weight = (const float*)d_in[3];
    const float* W           = (const float*)d_in[4];
    const float* b           = (const float*)d_in[5];
    float*       out         = (float*)d_out;

    int n = in_sizes[0] / D;
    int E = in_sizes[1];
    int nb = (n + TILE - 1) / TILE;
    int nchunks = (E + CHUNK_E - 1) / CHUNK_E;

    // workspace layout (256B-aligned slabs)
    char* ws = (char*)d_ws;
    auto al = [](size_t x) { return (x + 255) & ~(size_t)255; };
    size_t o = 0;
    int* deg      = (int*)(ws + o); o += al((size_t)n * 4);
    int* cursor   = (int*)(ws + o); o += al((size_t)n * 4);
    int* offsets  = (int*)(ws + o); o += al((size_t)(n + 1) * 4);
    int* partial  = (int*)(ws + o); o += al((size_t)nb * 4);
    int* ppref    = (int*)(ws + o); o += al((size_t)nb * 4);
    int2* csr_sw  = (int2*)(ws + o); o += al((size_t)E * 8);
    float* neighbor = (float*)(ws + o);

    hipMemsetAsync(deg, 0, (size_t)n * 4, stream);

    hist_kernel<<<nchunks * RB, 256, 0, stream>>>(edge_dst, deg, E, n);
    tile_sum_kernel<<<nb, 256, 0, stream>>>(deg, partial, n);
    scan_partial_kernel<<<1, 64, 0, stream>>>(partial, ppref, nb, offsets, n, E);
    scan_tile_kernel<<<nb, 256, 0, stream>>>(deg, ppref, offsets, cursor, n);
    fill_kernel<<<nchunks * RB, 256, 0, stream>>>(edge_src, edge_dst, edge_weight,
                                                  cursor, csr_sw, E, n);
    gather_kernel<<<2048, 256, 0, stream>>>(features, csr_sw, offsets,
                                            neighbor, n);
    gemm_norm_kernel<<<1024, 256, 0, stream>>>(features, neighbor, W, b, out, n);
}